// Round 3
// baseline (809.873 us; speedup 1.0000x reference)
//
#include <hip/hip_runtime.h>
#include <math.h>

// Reference is fp32: all d_in are const float*, d_out is float*.
// Internal compute in bf16 (threshold = 2% of |ref|max permits it).
// B=4 S=2048 H=16 DH=64 D=1024; FF_IN=4096 FF_HID=2048.

typedef __bf16 bf16;
typedef bf16 bf16x8 __attribute__((ext_vector_type(8)));
typedef float f32x4 __attribute__((ext_vector_type(4)));

#define LDSP 72  // LDS row stride (bf16): mult of 8 keeps ds_read_b128 aligned

// ---------------------------------------------------------------------------
// Diagnostic: fill out with 0.25 if ws_size too small (absmax ~5.31, not NaN).
// ---------------------------------------------------------------------------
__global__ __launch_bounds__(256) void fill_sentinel(float* __restrict__ o)
{
    size_t i = ((size_t)blockIdx.x * 256 + threadIdx.x) * 4;
    float4 v = make_float4(0.25f, 0.25f, 0.25f, 0.25f);
    *(float4*)&o[i] = v;
}

// ---------------------------------------------------------------------------
// Weight transpose + convert: in fp32 [K][N] -> out bf16 [N][K], 64x64 tiles.
// ---------------------------------------------------------------------------
__global__ __launch_bounds__(256) void transpose_f32_bf16(
    const float* __restrict__ in, bf16* __restrict__ out, int K, int N)
{
    __shared__ bf16 T[64][LDSP];
    const int tN = N >> 6;
    const int tk = blockIdx.x / tN, tn = blockIdx.x % tN;
    const int k0 = tk << 6, n0 = tn << 6;
    const int t = threadIdx.x;
    const int r = t >> 2, c0 = (t & 3) << 4;
    const float* src = &in[(size_t)(k0 + r) * N + n0 + c0];
    for (int j = 0; j < 4; ++j) {
        float4 f = *(const float4*)(src + 4 * j);
        T[r][c0 + 4 * j + 0] = (bf16)f.x;
        T[r][c0 + 4 * j + 1] = (bf16)f.y;
        T[r][c0 + 4 * j + 2] = (bf16)f.z;
        T[r][c0 + 4 * j + 3] = (bf16)f.w;
    }
    __syncthreads();
    bf16x8 o0, o1;
    for (int i = 0; i < 8; ++i) o0[i] = T[c0 + i][r];
    for (int i = 0; i < 8; ++i) o1[i] = T[c0 + 8 + i][r];
    *(bf16x8*)&out[(size_t)(n0 + r) * K + k0 + c0]     = o0;
    *(bf16x8*)&out[(size_t)(n0 + r) * K + k0 + c0 + 8] = o1;
}

// ---------------------------------------------------------------------------
// GEMM: C[M,N] = A[M,K(lda)] @ BT[N,K]^T + bias.  128x128 tile, 4 waves, BK=64.
// AF32: A is fp32 (converted during staging); else A is bf16.
// EPI 0: scatter qkv -> C0/C1/C2 as [B,H,S,DH] (col = h*192 + t*64 + d), bf16
// EPI 1: plain bf16 store C0[M,N]
// EPI 2: fp32 store Cf = val + resid (residual add, resid bf16)
// ---------------------------------------------------------------------------
template <int EPI, bool AF32>
__global__ __launch_bounds__(256) void gemm_bt(
    const void* __restrict__ Avp, const bf16* __restrict__ BT,
    const float* __restrict__ bias, int M, int N, int K, int lda,
    bf16* __restrict__ C0, bf16* __restrict__ C1, bf16* __restrict__ C2,
    float* __restrict__ Cf, const bf16* __restrict__ resid)
{
    __shared__ bf16 As[128][LDSP];
    __shared__ bf16 Bs[128][LDSP];
    const int tid = threadIdx.x;
    const int lane = tid & 63, wave = tid >> 6;
    const int quad = lane >> 4, l16 = lane & 15;
    const int wm = wave >> 1, wn = wave & 1;
    const int nb = N >> 7;
    const int bm = blockIdx.x / nb, bn = blockIdx.x % nb;
    const int m0 = bm << 7, n0 = bn << 7;
    const float* Af = (const float*)Avp;
    const bf16*  Ab = (const bf16*)Avp;

    f32x4 acc[4][4] = {};

    for (int kt = 0; kt < K; kt += 64) {
        for (int i = 0; i < 4; ++i) {
            int c = tid + (i << 8);           // 1024 16B-chunks per tile
            int r = c >> 3, cc = (c & 7) << 3;
            if (AF32) {
                const float* s = &Af[(size_t)(m0 + r) * lda + kt + cc];
                float4 f0 = *(const float4*)s;
                float4 f1 = *(const float4*)(s + 4);
                bf16x8 tv;
                tv[0] = (bf16)f0.x; tv[1] = (bf16)f0.y;
                tv[2] = (bf16)f0.z; tv[3] = (bf16)f0.w;
                tv[4] = (bf16)f1.x; tv[5] = (bf16)f1.y;
                tv[6] = (bf16)f1.z; tv[7] = (bf16)f1.w;
                *(bf16x8*)&As[r][cc] = tv;
            } else {
                *(bf16x8*)&As[r][cc] = *(const bf16x8*)&Ab[(size_t)(m0 + r) * lda + kt + cc];
            }
            *(bf16x8*)&Bs[r][cc] = *(const bf16x8*)&BT[(size_t)(n0 + r) * K + kt + cc];
        }
        __syncthreads();
        for (int kd = 0; kd < 2; ++kd) {
            bf16x8 af[4], bfr[4];
            for (int mi = 0; mi < 4; ++mi)
                af[mi] = *(const bf16x8*)&As[(wm << 6) + (mi << 4) + l16][(kd << 5) + (quad << 3)];
            for (int ni = 0; ni < 4; ++ni)
                bfr[ni] = *(const bf16x8*)&Bs[(wn << 6) + (ni << 4) + l16][(kd << 5) + (quad << 3)];
            for (int mi = 0; mi < 4; ++mi)
                for (int ni = 0; ni < 4; ++ni)
                    acc[mi][ni] = __builtin_amdgcn_mfma_f32_16x16x32_bf16(
                        af[mi], bfr[ni], acc[mi][ni], 0, 0, 0);
        }
        __syncthreads();
    }

    for (int mi = 0; mi < 4; ++mi) {
        for (int ni = 0; ni < 4; ++ni) {
            for (int r = 0; r < 4; ++r) {
                int row = m0 + (wm << 6) + (mi << 4) + (quad << 2) + r;
                int col = n0 + (wn << 6) + (ni << 4) + l16;
                float v = acc[mi][ni][r] + bias[col];
                if (EPI == 0) {
                    int b = row >> 11, s = row & 2047;
                    int h = col / 192, w = col % 192;
                    int tq = w >> 6, d = w & 63;
                    bf16* dst = (tq == 0) ? C0 : (tq == 1) ? C1 : C2;
                    dst[((((size_t)b * 16 + h) * 2048 + s) << 6) + d] = (bf16)v;
                } else if (EPI == 1) {
                    C0[(size_t)row * N + col] = (bf16)v;
                } else {
                    float rv = (float)resid[(size_t)row * N + col];
                    Cf[(size_t)row * N + col] = v + rv;
                }
            }
        }
    }
}

// ---------------------------------------------------------------------------
// Fused l2norm + head-scale + xpos RoPE, in place on q_buf / k_buf [64,2048,64].
// One wave per (bh, s) row, lane = d.
// ---------------------------------------------------------------------------
__global__ __launch_bounds__(256) void norm_rope(
    bf16* __restrict__ qb, bf16* __restrict__ kb,
    const float* __restrict__ qs, const float* __restrict__ ks)
{
    const int wave = threadIdx.x >> 6, lane = threadIdx.x & 63;
    const int rid = blockIdx.x * 4 + wave;          // 0 .. 262143
    const bool is_k = rid >= 131072;
    const int idx = is_k ? rid - 131072 : rid;      // bh*2048 + s
    const int s = idx & 2047;
    bf16* ptr = (is_k ? kb : qb) + ((size_t)idx << 6);
    const int d = lane;

    float v = (float)ptr[d];
    float ss = v * v;
    for (int o = 1; o < 64; o <<= 1) ss += __shfl_xor(ss, o);
    float nrm = sqrtf(ss);
    float scl = (is_k ? ks : qs)[d];
    float t = v / fmaxf(nrm, 1e-12f) * scl;

    float partner = __shfl_xor(t, 32);
    float rh = (d < 32) ? -partner : partner;       // rotate_half

    const int i = d & 31;
    float inv_freq = powf(10000.0f, -(float)(2 * i) / 64.0f);
    float pos = (float)s * inv_freq;
    float base = ((float)(2 * i) + 25.6f) / 89.6f;  // (2i + 0.4*64)/(1.4*64)
    float power = ((float)s - 1024.0f) / 512.0f;
    if (is_k) power = -power;
    float xsc = powf(base, power);
    float ov = t * cosf(pos) * xsc + rh * sinf(pos) * xsc;
    ptr[d] = (bf16)ov;
}

// ---------------------------------------------------------------------------
// Flash attention (non-causal). Block = (bh, 64 q-rows); 4 waves x 16 rows.
// K tile [64,64] staged natural; V staged transposed; P via LDS round-trip.
// ---------------------------------------------------------------------------
__global__ __launch_bounds__(256) void attn(
    const bf16* __restrict__ Q, const bf16* __restrict__ Kb,
    const bf16* __restrict__ V, bf16* __restrict__ O)
{
    __shared__ bf16 Ks[64][LDSP];
    __shared__ bf16 Vt[64][LDSP];      // Vt[d][j]
    __shared__ bf16 Ps[4][16][LDSP];   // per-wave P tile
    const int tid = threadIdx.x;
    const int lane = tid & 63, wave = tid >> 6;
    const int quad = lane >> 4, l16 = lane & 15;
    const int bh = blockIdx.x >> 5;
    const int q0 = (blockIdx.x & 31) << 6;
    const bf16* Qp = Q + ((size_t)bh << 17);
    const bf16* Kp = Kb + ((size_t)bh << 17);
    const bf16* Vp = V + ((size_t)bh << 17);

    bf16x8 qf[2];
    {
        const bf16* qrow = Qp + (size_t)(q0 + (wave << 4) + l16) * 64;
        qf[0] = *(const bf16x8*)&qrow[(quad << 3)];
        qf[1] = *(const bf16x8*)&qrow[32 + (quad << 3)];
    }
    float m_i[4], l_i[4];
    f32x4 oacc[4] = {};
    for (int r = 0; r < 4; ++r) { m_i[r] = -INFINITY; l_i[r] = 0.0f; }

    for (int kt = 0; kt < 2048; kt += 64) {
        __syncthreads();  // protect Vt/Ps reads of previous tile
        {
            int j = tid >> 2, d0 = (tid & 3) << 4;     // K stage: contiguous copy
            const bf16* src = Kp + (size_t)(kt + j) * 64 + d0;
            *(bf16x8*)&Ks[j][d0]     = *(const bf16x8*)src;
            *(bf16x8*)&Ks[j][d0 + 8] = *(const bf16x8*)(src + 8);
            int j2 = tid & 63, i0 = (tid >> 6) << 4;   // V stage: transpose
            const bf16* vs = Vp + (size_t)(kt + j2) * 64 + i0;
            bf16x8 v0 = *(const bf16x8*)vs;
            bf16x8 v1 = *(const bf16x8*)(vs + 8);
            for (int i = 0; i < 8; ++i) Vt[i0 + i][j2] = v0[i];
            for (int i = 0; i < 8; ++i) Vt[i0 + 8 + i][j2] = v1[i];
        }
        __syncthreads();

        f32x4 sc[4];
        for (int nt = 0; nt < 4; ++nt) {
            bf16x8 kf0 = *(const bf16x8*)&Ks[(nt << 4) + l16][(quad << 3)];
            bf16x8 kf1 = *(const bf16x8*)&Ks[(nt << 4) + l16][32 + (quad << 3)];
            f32x4 z = {};
            z = __builtin_amdgcn_mfma_f32_16x16x32_bf16(qf[0], kf0, z, 0, 0, 0);
            z = __builtin_amdgcn_mfma_f32_16x16x32_bf16(qf[1], kf1, z, 0, 0, 0);
            sc[nt] = z;
        }
        for (int nt = 0; nt < 4; ++nt) sc[nt] *= 0.125f;  // 1/sqrt(64)

        float alpha[4];
        for (int r = 0; r < 4; ++r) {
            float rm = fmaxf(fmaxf(sc[0][r], sc[1][r]), fmaxf(sc[2][r], sc[3][r]));
            for (int o = 1; o < 16; o <<= 1) rm = fmaxf(rm, __shfl_xor(rm, o));
            float mn = fmaxf(m_i[r], rm);
            alpha[r] = __expf(m_i[r] - mn);
            m_i[r] = mn;
            float rs = 0.0f;
            for (int nt = 0; nt < 4; ++nt) {
                float p = __expf(sc[nt][r] - mn);
                sc[nt][r] = p;
                rs += p;
            }
            for (int o = 1; o < 16; o <<= 1) rs += __shfl_xor(rs, o);
            l_i[r] = alpha[r] * l_i[r] + rs;
        }
        for (int r = 0; r < 4; ++r)
            for (int nt = 0; nt < 4; ++nt)
                Ps[wave][(quad << 2) + r][(nt << 4) + l16] = (bf16)sc[nt][r];
        for (int ntd = 0; ntd < 4; ++ntd)
            for (int r = 0; r < 4; ++r) oacc[ntd][r] *= alpha[r];
        __syncthreads();  // Ps visible

        bf16x8 pf0 = *(const bf16x8*)&Ps[wave][l16][(quad << 3)];
        bf16x8 pf1 = *(const bf16x8*)&Ps[wave][l16][32 + (quad << 3)];
        for (int ntd = 0; ntd < 4; ++ntd) {
            bf16x8 vf0 = *(const bf16x8*)&Vt[(ntd << 4) + l16][(quad << 3)];
            bf16x8 vf1 = *(const bf16x8*)&Vt[(ntd << 4) + l16][32 + (quad << 3)];
            oacc[ntd] = __builtin_amdgcn_mfma_f32_16x16x32_bf16(pf0, vf0, oacc[ntd], 0, 0, 0);
            oacc[ntd] = __builtin_amdgcn_mfma_f32_16x16x32_bf16(pf1, vf1, oacc[ntd], 0, 0, 0);
        }
    }

    const int b = bh >> 4, h = bh & 15;
    for (int r = 0; r < 4; ++r) {
        int srow = q0 + (wave << 4) + (quad << 2) + r;
        float inv_l = 1.0f / l_i[r];
        for (int ntd = 0; ntd < 4; ++ntd) {
            int d = (ntd << 4) + l16;
            O[((((size_t)b * 2048 + srow) * 16) + h) * 64 + d] = (bf16)(oacc[ntd][r] * inv_l);
        }
    }
}

// ---------------------------------------------------------------------------
// LayerNorm over rows of [8192, 1024]; gamma/beta fp32.
// ---------------------------------------------------------------------------
__global__ __launch_bounds__(256) void layernorm(
    const bf16* __restrict__ x, const float* __restrict__ g,
    const float* __restrict__ b, bf16* __restrict__ y)
{
    __shared__ float red[8];
    const int row = blockIdx.x;
    const int t = threadIdx.x;
    const bf16* xr = x + ((size_t)row << 10);
    bf16x8 xv = *(const bf16x8*)&xr[t << 2];  // note: only first 4 used? no — use 4-wide
    float v[4], s = 0.0f, sq = 0.0f;
    for (int i = 0; i < 4; ++i) { v[i] = (float)xv[i]; s += v[i]; sq += v[i] * v[i]; }
    for (int o = 1; o < 64; o <<= 1) { s += __shfl_xor(s, o); sq += __shfl_xor(sq, o); }
    const int wave = t >> 6, lane = t & 63;
    if (lane == 0) { red[wave] = s; red[4 + wave] = sq; }
    __syncthreads();
    s  = red[0] + red[1] + red[2] + red[3];
    sq = red[4] + red[5] + red[6] + red[7];
    float mu = s * (1.0f / 1024.0f);
    float var = fmaxf(sq * (1.0f / 1024.0f) - mu * mu, 0.0f);
    float rstd = rsqrtf(var + 1e-5f);
    for (int i = 0; i < 4; ++i) {
        int c = (t << 2) + i;
        y[((size_t)row << 10) + c] = (bf16)((v[i] - mu) * rstd * g[c] + b[c]);
    }
}

// ---------------------------------------------------------------------------
// SwiGLU in place: h[r][c] = silu(h[r][c+2048]) * h[r][c], h is [8192,4096].
// ---------------------------------------------------------------------------
__global__ __launch_bounds__(256) void swiglu(bf16* __restrict__ h)
{
    size_t i = ((size_t)blockIdx.x * 256 + threadIdx.x) * 8;
    size_t row = i >> 11, c = i & 2047;
    bf16* hr = h + (row << 12);
    bf16x8 xv = *(const bf16x8*)&hr[c];
    bf16x8 gv = *(const bf16x8*)&hr[c + 2048];
    bf16x8 ov;
    for (int j = 0; j < 8; ++j) {
        float xf = (float)xv[j], gf = (float)gv[j];
        ov[j] = (bf16)(gf / (1.0f + __expf(-gf)) * xf);
    }
    *(bf16x8*)&hr[c] = ov;
}

// ---------------------------------------------------------------------------
// Orchestration. ws layout (bytes), peak 92 MiB:
//   W2T 0..4M | ln 4..20M | W1T 20..28M | q 28..44M k 44..60M v 60..76M
//   attn 76..92M | WqkvT 76..82M (overlay attn, dead before attn runs)
//   h 28..92M (overlays q/k/v/attn after attention is consumed)
// ---------------------------------------------------------------------------
extern "C" void kernel_launch(void* const* d_in, const int* in_sizes, int n_in,
                              void* d_out, int out_size, void* d_ws, size_t ws_size,
                              hipStream_t stream) {
    (void)in_sizes; (void)n_in; (void)out_size;
    const float* q    = (const float*)d_in[0];
    const float* Wqkv = (const float*)d_in[3];
    const float* bqkv = (const float*)d_in[4];
    const float* qsc  = (const float*)d_in[5];
    const float* ksc  = (const float*)d_in[6];
    const float* lng  = (const float*)d_in[7];
    const float* lnb  = (const float*)d_in[8];
    const float* W1   = (const float*)d_in[9];
    const float* b1   = (const float*)d_in[10];
    const float* W2   = (const float*)d_in[11];
    const float* b2   = (const float*)d_in[12];
    float* out = (float*)d_out;

    const size_t MB = 1024 * 1024;
    const size_t NEED = 92 * MB;
    if (ws_size < NEED) {   // diagnostic: absmax ~5.31 (not NaN) => ws too small
        fill_sentinel<<<8192, 256, 0, stream>>>(out);
        return;
    }

    char* ws = (char*)d_ws;
    bf16* W2T      = (bf16*)(ws + 0);
    bf16* ln_buf   = (bf16*)(ws + 4  * MB);
    bf16* W1T      = (bf16*)(ws + 20 * MB);
    bf16* q_buf    = (bf16*)(ws + 28 * MB);
    bf16* k_buf    = (bf16*)(ws + 44 * MB);
    bf16* v_buf    = (bf16*)(ws + 60 * MB);
    bf16* attn_buf = (bf16*)(ws + 76 * MB);
    bf16* WqkvT    = (bf16*)(ws + 76 * MB);  // overlay attn_buf (dead before attn)
    bf16* h_buf    = (bf16*)(ws + 28 * MB);  // overlay q/k/v/attn (dead after LN)

    transpose_f32_bf16<<<512,  256, 0, stream>>>(W2,   W2T,   2048, 1024);
    transpose_f32_bf16<<<1024, 256, 0, stream>>>(W1,   W1T,   1024, 4096);
    transpose_f32_bf16<<<768,  256, 0, stream>>>(Wqkv, WqkvT, 1024, 3072);

    gemm_bt<0, true><<<1536, 256, 0, stream>>>(q, WqkvT, bqkv, 8192, 3072, 1024, 1024,
                                               q_buf, k_buf, v_buf, nullptr, nullptr);
    norm_rope<<<65536, 256, 0, stream>>>(q_buf, k_buf, qsc, ksc);
    attn<<<2048, 256, 0, stream>>>(q_buf, k_buf, v_buf, attn_buf);
    layernorm<<<8192, 256, 0, stream>>>(attn_buf, lng, lnb, ln_buf);
    gemm_bt<1, false><<<2048, 256, 0, stream>>>(ln_buf, W1T, b1, 8192, 4096, 1024, 1024,
                                                h_buf, nullptr, nullptr, nullptr, nullptr);
    swiglu<<<8192, 256, 0, stream>>>(h_buf);
    gemm_bt<2, false><<<512, 256, 0, stream>>>(h_buf, W2T, b2, 8192, 1024, 2048, 4096,
                                               nullptr, nullptr, nullptr, out, ln_buf);
}

// Round 4
// 659.516 us; speedup vs baseline: 1.2280x; 1.2280x over previous
//
#include <hip/hip_runtime.h>
#include <math.h>

// Reference is fp32: all d_in are const float*, d_out is float*.
// Internal compute in bf16 (threshold = 2% of |ref|max permits it).
// B=4 S=2048 H=16 DH=64 D=1024; FF_IN=4096 FF_HID=2048.

typedef __bf16 bf16;
typedef bf16 bf16x8 __attribute__((ext_vector_type(8)));
typedef bf16 bf16x4 __attribute__((ext_vector_type(4)));
typedef float f32x4 __attribute__((ext_vector_type(4)));

#define MFMA(a, b, c) __builtin_amdgcn_mfma_f32_16x16x32_bf16(a, b, c, 0, 0, 0)

// Async global->LDS, 16B per lane. LDS dest must be wave-uniform base;
// HW adds lane*16. LDS tiles therefore unpadded (m104/m108 caveat).
__device__ __forceinline__ void async16(const void* g, void* l) {
    __builtin_amdgcn_global_load_lds(
        (const __attribute__((address_space(1))) void*)g,
        (__attribute__((address_space(3))) void*)l,
        16, 0, 0);
}

// ---------------------------------------------------------------------------
// Diagnostic: fill out with 0.25 if ws_size too small (absmax ~5.31, not NaN).
// ---------------------------------------------------------------------------
__global__ __launch_bounds__(256) void fill_sentinel(float* __restrict__ o)
{
    size_t i = ((size_t)blockIdx.x * 256 + threadIdx.x) * 4;
    *(float4*)&o[i] = make_float4(0.25f, 0.25f, 0.25f, 0.25f);
}

// ---------------------------------------------------------------------------
// Weight transpose + convert: in fp32 [K][N] -> out bf16 [N][K], 64x64 tiles.
// ---------------------------------------------------------------------------
__global__ __launch_bounds__(256) void transpose_f32_bf16(
    const float* __restrict__ in, bf16* __restrict__ out, int K, int N)
{
    __shared__ bf16 T[64][72];
    const int tN = N >> 6;
    const int tk = blockIdx.x / tN, tn = blockIdx.x % tN;
    const int k0 = tk << 6, n0 = tn << 6;
    const int t = threadIdx.x;
    const int r = t >> 2, c0 = (t & 3) << 4;
    const float* src = &in[(size_t)(k0 + r) * N + n0 + c0];
    for (int j = 0; j < 4; ++j) {
        float4 f = *(const float4*)(src + 4 * j);
        T[r][c0 + 4 * j + 0] = (bf16)f.x;
        T[r][c0 + 4 * j + 1] = (bf16)f.y;
        T[r][c0 + 4 * j + 2] = (bf16)f.z;
        T[r][c0 + 4 * j + 3] = (bf16)f.w;
    }
    __syncthreads();
    bf16x8 o0, o1;
    for (int i = 0; i < 8; ++i) o0[i] = T[c0 + i][r];
    for (int i = 0; i < 8; ++i) o1[i] = T[c0 + 8 + i][r];
    *(bf16x8*)&out[(size_t)(n0 + r) * K + k0 + c0]     = o0;
    *(bf16x8*)&out[(size_t)(n0 + r) * K + k0 + c0 + 8] = o1;
}

// ---------------------------------------------------------------------------
// V transpose: in[bh][s][d] -> out[bh][d][s] (bh=64, s=2048, d=64), bf16.
// ---------------------------------------------------------------------------
__global__ __launch_bounds__(256) void transpose_v(
    const bf16* __restrict__ in, bf16* __restrict__ out)
{
    __shared__ bf16 T[64][72];
    const int bh = blockIdx.x >> 5;
    const int s0 = (blockIdx.x & 31) << 6;
    const bf16* ip = in + ((size_t)bh << 17) + (size_t)s0 * 64;
    bf16* op = out + ((size_t)bh << 17) + s0;
    const int t = threadIdx.x;
    const int r = t >> 2, c0 = (t & 3) << 4;
    *(bf16x8*)&T[r][c0]     = *(const bf16x8*)&ip[r * 64 + c0];
    *(bf16x8*)&T[r][c0 + 8] = *(const bf16x8*)&ip[r * 64 + c0 + 8];
    __syncthreads();
    bf16x8 o0, o1;
    for (int i = 0; i < 8; ++i) o0[i] = T[c0 + i][r];
    for (int i = 0; i < 8; ++i) o1[i] = T[c0 + 8 + i][r];
    *(bf16x8*)&op[(size_t)r * 2048 + c0]     = o0;
    *(bf16x8*)&op[(size_t)r * 2048 + c0 + 8] = o1;
}

// ---------------------------------------------------------------------------
// GEMM: C[M,N] = A[M,K(lda)] @ BT[N,K]^T + bias.  128x128 tile, 4 waves, BK=64.
// m97 recipe: unpadded [128][64] LDS + global_load_lds width-16 staging.
// AF32: A fp32 -> manual convert staging (Bs still async).
// EPI 0: scatter qkv -> C0/C1/C2 as [B,H,S,DH];  EPI 1: bf16 C0;
// EPI 2: fp32 Cf = val + resid.
// ---------------------------------------------------------------------------
template <int EPI, bool AF32>
__global__ __launch_bounds__(256) void gemm_bt(
    const void* __restrict__ Avp, const bf16* __restrict__ BT,
    const float* __restrict__ bias, int M, int N, int K, int lda,
    bf16* __restrict__ C0, bf16* __restrict__ C1, bf16* __restrict__ C2,
    float* __restrict__ Cf, const bf16* __restrict__ resid)
{
    __shared__ bf16 As[128][64];
    __shared__ bf16 Bs[128][64];
    const int tid = threadIdx.x;
    const int lane = tid & 63, wave = tid >> 6;
    const int quad = lane >> 4, l16 = lane & 15;
    const int wm = wave >> 1, wn = wave & 1;
    const int nb = N >> 7;
    const int bm = blockIdx.x / nb, bn = blockIdx.x % nb;
    const int m0 = bm << 7, n0 = bn << 7;
    const float* Af = (const float*)Avp;
    const bf16*  Ab = (const bf16*)Avp;
    char* aB = (char*)&As[0][0];
    char* bB = (char*)&Bs[0][0];

    f32x4 acc[4][4] = {};

    for (int kt = 0; kt < K; kt += 64) {
        for (int i = 0; i < 4; ++i) {
            int c  = (i << 8) + tid;
            int cu = (i << 8) + (wave << 6);
            if (!AF32)
                async16(&Ab[(size_t)(m0 + (c >> 3)) * lda + kt + ((c & 7) << 3)],
                        aB + (size_t)cu * 16);
            async16(&BT[(size_t)(n0 + (c >> 3)) * K + kt + ((c & 7) << 3)],
                    bB + (size_t)cu * 16);
        }
        if (AF32) {
            for (int i = 0; i < 4; ++i) {
                int c = (i << 8) + tid;
                int r = c >> 3, cc = (c & 7) << 3;
                const float* s = &Af[(size_t)(m0 + r) * lda + kt + cc];
                float4 f0 = *(const float4*)s;
                float4 f1 = *(const float4*)(s + 4);
                bf16x8 tv;
                tv[0] = (bf16)f0.x; tv[1] = (bf16)f0.y;
                tv[2] = (bf16)f0.z; tv[3] = (bf16)f0.w;
                tv[4] = (bf16)f1.x; tv[5] = (bf16)f1.y;
                tv[6] = (bf16)f1.z; tv[7] = (bf16)f1.w;
                *(bf16x8*)&As[r][cc] = tv;
            }
        }
        __syncthreads();
        for (int kd = 0; kd < 2; ++kd) {
            bf16x8 af[4], bfr[4];
            for (int mi = 0; mi < 4; ++mi)
                af[mi] = *(const bf16x8*)&As[(wm << 6) + (mi << 4) + l16][(kd << 5) + (quad << 3)];
            for (int ni = 0; ni < 4; ++ni)
                bfr[ni] = *(const bf16x8*)&Bs[(wn << 6) + (ni << 4) + l16][(kd << 5) + (quad << 3)];
            for (int mi = 0; mi < 4; ++mi)
                for (int ni = 0; ni < 4; ++ni)
                    acc[mi][ni] = MFMA(af[mi], bfr[ni], acc[mi][ni]);
        }
        __syncthreads();
    }

    for (int mi = 0; mi < 4; ++mi) {
        for (int ni = 0; ni < 4; ++ni) {
            for (int r = 0; r < 4; ++r) {
                int row = m0 + (wm << 6) + (mi << 4) + (quad << 2) + r;
                int col = n0 + (wn << 6) + (ni << 4) + l16;
                float v = acc[mi][ni][r] + bias[col];
                if (EPI == 0) {
                    int b = row >> 11, s = row & 2047;
                    int h = col / 192, w = col % 192;
                    int tq = w >> 6, d = w & 63;
                    bf16* dst = (tq == 0) ? C0 : (tq == 1) ? C1 : C2;
                    dst[((((size_t)b * 16 + h) * 2048 + s) << 6) + d] = (bf16)v;
                } else if (EPI == 1) {
                    C0[(size_t)row * N + col] = (bf16)v;
                } else {
                    float rv = (float)resid[(size_t)row * N + col];
                    Cf[(size_t)row * N + col] = v + rv;
                }
            }
        }
    }
}

// ---------------------------------------------------------------------------
// Fused l2norm + head-scale + xpos RoPE, in place, HW transcendentals.
// One wave per (bh, s) row, lane = d.
// ---------------------------------------------------------------------------
__global__ __launch_bounds__(256) void norm_rope(
    bf16* __restrict__ qb, bf16* __restrict__ kb,
    const float* __restrict__ qs, const float* __restrict__ ks)
{
    const int wave = threadIdx.x >> 6, lane = threadIdx.x & 63;
    const int rid = blockIdx.x * 4 + wave;          // 0 .. 262143
    const bool is_k = rid >= 131072;
    const int idx = is_k ? rid - 131072 : rid;      // bh*2048 + s
    const int s = idx & 2047;
    bf16* ptr = (is_k ? kb : qb) + ((size_t)idx << 6);
    const int d = lane;

    float v = (float)ptr[d];
    float ss = v * v;
    for (int o = 1; o < 64; o <<= 1) ss += __shfl_xor(ss, o);
    float t = v * rsqrtf(fmaxf(ss, 1e-24f));
    t *= (is_k ? ks : qs)[d];

    float partner = __shfl_xor(t, 32);
    float rh = (d < 32) ? -partner : partner;       // rotate_half

    const float fi = (float)(d & 31);
    // 10000^(-2i/64) = exp2(-i * log2(10000)/32)
    float inv_freq = __builtin_amdgcn_exp2f(fi * -0.4152410118609203f);
    float pos = (float)s * inv_freq;
    float rev = pos * 0.15915494309189535f;         // v_sin takes revolutions
    rev = rev - floorf(rev);
    float sn = __builtin_amdgcn_sinf(rev);
    float cs = __builtin_amdgcn_cosf(rev);
    float base = (2.0f * fi + 25.6f) * (1.0f / 89.6f);
    float power = ((float)s - 1024.0f) * (1.0f / 512.0f);
    if (is_k) power = -power;
    float xsc = __builtin_amdgcn_exp2f(power * __builtin_amdgcn_logf(base));
    ptr[d] = (bf16)((t * cs + rh * sn) * xsc);
}

// ---------------------------------------------------------------------------
// Flash attention, no-max softmax (scores/8 provably <= ~19 -> exp <= 1.4e8,
// fp32-safe). 0.125*log2e folded into Q frag; P = exp2(score).
// Row-sums via ones-column MFMA (lane-0 B-frag). K/V^T staged async.
// Block = (bh, 64 q-rows); 4 waves x 16 rows.
// ---------------------------------------------------------------------------
__global__ __launch_bounds__(256) void attn(
    const bf16* __restrict__ Q, const bf16* __restrict__ Kb,
    const bf16* __restrict__ VT, bf16* __restrict__ O)
{
    __shared__ bf16 Ks[64][64];
    __shared__ bf16 Vt[64][64];        // Vt[d][j]
    __shared__ bf16 Ps[4][16][72];     // per-wave P tile, +8*quad col rotation
    const int tid = threadIdx.x;
    const int lane = tid & 63, wave = tid >> 6;
    const int quad = lane >> 4, l16 = lane & 15;
    const int bh = blockIdx.x >> 5;
    const int q0 = (blockIdx.x & 31) << 6;
    const bf16* Qp = Q + ((size_t)bh << 17);
    const bf16* Kp = Kb + ((size_t)bh << 17);
    const bf16* Vp = VT + ((size_t)bh << 17);

    bf16x8 qf[2];
    {
        const bf16* qrow = Qp + (size_t)(q0 + (wave << 4) + l16) * 64;
        qf[0] = *(const bf16x8*)&qrow[(quad << 3)];
        qf[1] = *(const bf16x8*)&qrow[32 + (quad << 3)];
        for (int j = 0; j < 8; ++j) {   // fold 0.125 * log2(e) into Q
            qf[0][j] = (bf16)((float)qf[0][j] * 0.1803368801f);
            qf[1][j] = (bf16)((float)qf[1][j] * 0.1803368801f);
        }
    }
    bf16x8 ones = {};
    if (l16 == 0) for (int j = 0; j < 8; ++j) ones[j] = (bf16)1.0f;

    f32x4 oacc[4] = {};
    f32x4 lacc = {};
    char* kB = (char*)&Ks[0][0];
    char* vB = (char*)&Vt[0][0];

    for (int kt = 0; kt < 2048; kt += 64) {
        __syncthreads();               // all waves done reading prev Ks/Vt
        for (int i = 0; i < 2; ++i) {
            int c  = (i << 8) + tid;
            int cu = (i << 8) + (wave << 6);
            async16(&Kp[(size_t)(kt + (c >> 3)) * 64 + ((c & 7) << 3)],
                    kB + (size_t)cu * 16);
            async16(&Vp[(size_t)(c >> 3) * 2048 + kt + ((c & 7) << 3)],
                    vB + (size_t)cu * 16);
        }
        __syncthreads();               // drains vmcnt: tiles resident

        f32x4 sc[4];
        for (int nt = 0; nt < 4; ++nt) {
            bf16x8 kf0 = *(const bf16x8*)&Ks[(nt << 4) + l16][(quad << 3)];
            bf16x8 kf1 = *(const bf16x8*)&Ks[(nt << 4) + l16][32 + (quad << 3)];
            f32x4 z = {};
            z = MFMA(qf[0], kf0, z);
            z = MFMA(qf[1], kf1, z);
            sc[nt] = z;
        }
        const int prow = quad << 2;
        for (int r = 0; r < 4; ++r)
            for (int nt = 0; nt < 4; ++nt) {
                int ep = (((nt << 4) + l16) + (quad << 3)) & 63;
                Ps[wave][prow + r][ep] = (bf16)__builtin_amdgcn_exp2f(sc[nt][r]);
            }
        // Ps round-trip is wave-local: same-wave DS ops are in-order; the
        // wave_barrier pins compiler ordering. No s_barrier needed.
        __builtin_amdgcn_wave_barrier();
        const int rot = (l16 >> 2) << 3;
        bf16x8 pf0 = *(const bf16x8*)&Ps[wave][l16][((quad << 3) + rot) & 63];
        bf16x8 pf1 = *(const bf16x8*)&Ps[wave][l16][(32 + (quad << 3) + rot) & 63];
        for (int ntd = 0; ntd < 4; ++ntd) {
            bf16x8 vf0 = *(const bf16x8*)&Vt[(ntd << 4) + l16][(quad << 3)];
            bf16x8 vf1 = *(const bf16x8*)&Vt[(ntd << 4) + l16][32 + (quad << 3)];
            oacc[ntd] = MFMA(pf0, vf0, oacc[ntd]);
            oacc[ntd] = MFMA(pf1, vf1, oacc[ntd]);
        }
        lacc = MFMA(pf0, ones, lacc);  // row-sums accumulate in col 0
        lacc = MFMA(pf1, ones, lacc);
    }

    const int b = bh >> 4, h = bh & 15;
    for (int r = 0; r < 4; ++r) {
        float l = __shfl(lacc[r], quad << 4);   // col-0 lane of this quad
        float inv_l = 1.0f / l;
        int srow = q0 + (wave << 4) + (quad << 2) + r;
        for (int ntd = 0; ntd < 4; ++ntd) {
            int d = (ntd << 4) + l16;
            O[((((size_t)b * 2048 + srow) * 16) + h) * 64 + d] = (bf16)(oacc[ntd][r] * inv_l);
        }
    }
}

// ---------------------------------------------------------------------------
// LayerNorm over rows of [8192, 1024]; gamma/beta fp32.
// ---------------------------------------------------------------------------
__global__ __launch_bounds__(256) void layernorm(
    const bf16* __restrict__ x, const float* __restrict__ g,
    const float* __restrict__ b, bf16* __restrict__ y)
{
    __shared__ float red[8];
    const int row = blockIdx.x;
    const int t = threadIdx.x;
    const bf16* xr = x + ((size_t)row << 10);
    bf16x4 xv = *(const bf16x4*)&xr[t << 2];
    float v[4], s = 0.0f, sq = 0.0f;
    for (int i = 0; i < 4; ++i) { v[i] = (float)xv[i]; s += v[i]; sq += v[i] * v[i]; }
    for (int o = 1; o < 64; o <<= 1) { s += __shfl_xor(s, o); sq += __shfl_xor(sq, o); }
    const int wave = t >> 6, lane = t & 63;
    if (lane == 0) { red[wave] = s; red[4 + wave] = sq; }
    __syncthreads();
    s  = red[0] + red[1] + red[2] + red[3];
    sq = red[4] + red[5] + red[6] + red[7];
    float mu = s * (1.0f / 1024.0f);
    float var = fmaxf(sq * (1.0f / 1024.0f) - mu * mu, 0.0f);
    float rstd = rsqrtf(var + 1e-5f);
    bf16x4 ov;
    for (int i = 0; i < 4; ++i) {
        int c = (t << 2) + i;
        ov[i] = (bf16)((v[i] - mu) * rstd * g[c] + b[c]);
    }
    *(bf16x4*)(y + ((size_t)row << 10) + (t << 2)) = ov;
}

// ---------------------------------------------------------------------------
// SwiGLU in place: h[r][c] = silu(h[r][c+2048]) * h[r][c], h is [8192,4096].
// ---------------------------------------------------------------------------
__global__ __launch_bounds__(256) void swiglu(bf16* __restrict__ h)
{
    size_t i = ((size_t)blockIdx.x * 256 + threadIdx.x) * 8;
    size_t row = i >> 11, c = i & 2047;
    bf16* hr = h + (row << 12);
    bf16x8 xv = *(const bf16x8*)&hr[c];
    bf16x8 gv = *(const bf16x8*)&hr[c + 2048];
    bf16x8 ov;
    for (int j = 0; j < 8; ++j) {
        float xf = (float)xv[j], gf = (float)gv[j];
        ov[j] = (bf16)(gf / (1.0f + __expf(-gf)) * xf);
    }
    *(bf16x8*)&hr[c] = ov;
}

// ---------------------------------------------------------------------------
// Orchestration. ws layout (bytes), peak 92 MiB:
//   W2T 0..4M | ln 4..20M | W1T 20..28M | q 28..44M k 44..60M v 60..76M
//   WqkvT 76..82M (dead after QKV gemm) | vt 76..92M (after transpose_v)
//   attn 60..76M (overlay v, dead after transpose_v)
//   h 28..92M (overlay q/k/vt/attn after LN consumed attn)
// ---------------------------------------------------------------------------
extern "C" void kernel_launch(void* const* d_in, const int* in_sizes, int n_in,
                              void* d_out, int out_size, void* d_ws, size_t ws_size,
                              hipStream_t stream) {
    (void)in_sizes; (void)n_in; (void)out_size;
    const float* q    = (const float*)d_in[0];
    const float* Wqkv = (const float*)d_in[3];
    const float* bqkv = (const float*)d_in[4];
    const float* qsc  = (const float*)d_in[5];
    const float* ksc  = (const float*)d_in[6];
    const float* lng  = (const float*)d_in[7];
    const float* lnb  = (const float*)d_in[8];
    const float* W1   = (const float*)d_in[9];
    const float* b1   = (const float*)d_in[10];
    const float* W2   = (const float*)d_in[11];
    const float* b2   = (const float*)d_in[12];
    float* out = (float*)d_out;

    const size_t MB = 1024 * 1024;
    if (ws_size < 92 * MB) {
        fill_sentinel<<<8192, 256, 0, stream>>>(out);
        return;
    }

    char* ws = (char*)d_ws;
    bf16* W2T      = (bf16*)(ws + 0);
    bf16* ln_buf   = (bf16*)(ws + 4  * MB);
    bf16* W1T      = (bf16*)(ws + 20 * MB);
    bf16* q_buf    = (bf16*)(ws + 28 * MB);
    bf16* k_buf    = (bf16*)(ws + 44 * MB);
    bf16* v_buf    = (bf16*)(ws + 60 * MB);
    bf16* WqkvT    = (bf16*)(ws + 76 * MB);
    bf16* vt_buf   = (bf16*)(ws + 76 * MB);  // overlays WqkvT (dead post-QKV)
    bf16* attn_buf = (bf16*)(ws + 60 * MB);  // overlays v_buf (dead post-transpose_v)
    bf16* h_buf    = (bf16*)(ws + 28 * MB);  // overlays q/k/vt/attn

    transpose_f32_bf16<<<512,  256, 0, stream>>>(W2,   W2T,   2048, 1024);
    transpose_f32_bf16<<<1024, 256, 0, stream>>>(W1,   W1T,   1024, 4096);
    transpose_f32_bf16<<<768,  256, 0, stream>>>(Wqkv, WqkvT, 1024, 3072);

    gemm_bt<0, true><<<1536, 256, 0, stream>>>(q, WqkvT, bqkv, 8192, 3072, 1024, 1024,
                                               q_buf, k_buf, v_buf, nullptr, nullptr);
    norm_rope<<<65536, 256, 0, stream>>>(q_buf, k_buf, qsc, ksc);
    transpose_v<<<2048, 256, 0, stream>>>(v_buf, vt_buf);
    attn<<<2048, 256, 0, stream>>>(q_buf, k_buf, vt_buf, attn_buf);
    layernorm<<<8192, 256, 0, stream>>>(attn_buf, lng, lnb, ln_buf);
    gemm_bt<1, false><<<2048, 256, 0, stream>>>(ln_buf, W1T, b1, 8192, 4096, 1024, 1024,
                                                h_buf, nullptr, nullptr, nullptr, nullptr);
    swiglu<<<8192, 256, 0, stream>>>(h_buf);
    gemm_bt<2, false><<<512, 256, 0, stream>>>(h_buf, W2T, b2, 8192, 1024, 2048, 4096,
                                               nullptr, nullptr, nullptr, out, ln_buf);
}

// Round 5
// 562.185 us; speedup vs baseline: 1.4406x; 1.1731x over previous
//
#include <hip/hip_runtime.h>
#include <math.h>

// Reference is fp32: all d_in are const float*, d_out is float*.
// Internal compute in bf16 (threshold = 2% of |ref|max permits it).
// B=4 S=2048 H=16 DH=64 D=1024; FF_IN=4096 FF_HID=2048.

typedef __bf16 bf16;
typedef bf16 bf16x8 __attribute__((ext_vector_type(8)));
typedef bf16 bf16x4 __attribute__((ext_vector_type(4)));
typedef float f32x4 __attribute__((ext_vector_type(4)));

#define MFMA(a, b, c) __builtin_amdgcn_mfma_f32_16x16x32_bf16(a, b, c, 0, 0, 0)

// Async global->LDS, 16B/lane; LDS dest = wave-uniform base + lane*16.
// XOR-swizzle (cb ^= row&7) is applied on the GLOBAL source index so the
// LDS image is swizzled; reads apply the same XOR -> 2-way banks (free).
__device__ __forceinline__ void async16(const void* g, void* l) {
    __builtin_amdgcn_global_load_lds(
        (const __attribute__((address_space(1))) void*)g,
        (__attribute__((address_space(3))) void*)l,
        16, 0, 0);
}

// ---------------------------------------------------------------------------
// Diagnostic: fill out with 0.25 if ws_size too small (absmax ~5.31, not NaN).
// ---------------------------------------------------------------------------
__global__ __launch_bounds__(256) void fill_sentinel(float* __restrict__ o)
{
    size_t i = ((size_t)blockIdx.x * 256 + threadIdx.x) * 4;
    *(float4*)&o[i] = make_float4(0.25f, 0.25f, 0.25f, 0.25f);
}

// ---------------------------------------------------------------------------
// Weight transpose + convert: fp32 [K][N] -> bf16 [N][K], 64x64 tiles.
// LDS stride 70: scalar-only access; breaks the 16-col bank degeneracy.
// ---------------------------------------------------------------------------
__global__ __launch_bounds__(256) void transpose_f32_bf16(
    const float* __restrict__ in, bf16* __restrict__ out, int K, int N)
{
    __shared__ bf16 T[64][70];
    const int tN = N >> 6;
    const int tk = blockIdx.x / tN, tn = blockIdx.x % tN;
    const int k0 = tk << 6, n0 = tn << 6;
    const int t = threadIdx.x;
    const int r = t >> 2, c0 = (t & 3) << 4;
    const float* src = &in[(size_t)(k0 + r) * N + n0 + c0];
    for (int j = 0; j < 4; ++j) {
        float4 f = *(const float4*)(src + 4 * j);
        T[r][c0 + 4 * j + 0] = (bf16)f.x;
        T[r][c0 + 4 * j + 1] = (bf16)f.y;
        T[r][c0 + 4 * j + 2] = (bf16)f.z;
        T[r][c0 + 4 * j + 3] = (bf16)f.w;
    }
    __syncthreads();
    bf16x8 o0, o1;
    for (int i = 0; i < 8; ++i) o0[i] = T[c0 + i][r];
    for (int i = 0; i < 8; ++i) o1[i] = T[c0 + 8 + i][r];
    *(bf16x8*)&out[(size_t)(n0 + r) * K + k0 + c0]     = o0;
    *(bf16x8*)&out[(size_t)(n0 + r) * K + k0 + c0 + 8] = o1;
}

// ---------------------------------------------------------------------------
// V transpose: in[bh][s][d] -> out[bh][d][s] (bh=64, s=2048, d=64), bf16.
// ---------------------------------------------------------------------------
__global__ __launch_bounds__(256) void transpose_v(
    const bf16* __restrict__ in, bf16* __restrict__ out)
{
    __shared__ bf16 T[64][72];
    const int bh = blockIdx.x >> 5;
    const int s0 = (blockIdx.x & 31) << 6;
    const bf16* ip = in + ((size_t)bh << 17) + (size_t)s0 * 64;
    bf16* op = out + ((size_t)bh << 17) + s0;
    const int t = threadIdx.x;
    const int r = t >> 2, c0 = (t & 3) << 4;
    *(bf16x8*)&T[r][c0]     = *(const bf16x8*)&ip[r * 64 + c0];
    *(bf16x8*)&T[r][c0 + 8] = *(const bf16x8*)&ip[r * 64 + c0 + 8];
    __syncthreads();
    bf16x8 o0, o1;
    for (int i = 0; i < 8; ++i) o0[i] = T[c0 + i][r];
    for (int i = 0; i < 8; ++i) o1[i] = T[c0 + 8 + i][r];
    *(bf16x8*)&op[(size_t)r * 2048 + c0]     = o0;
    *(bf16x8*)&op[(size_t)r * 2048 + c0 + 8] = o1;
}

// ---------------------------------------------------------------------------
// GEMM: C[M,N] = A[M,K(lda)] @ BT[N,K]^T + bias. 128x128 tile, 4 waves, BK=64.
// Flat LDS with xor-swizzled chunks (chunk = row*8 + (cb ^ (row&7))).
// AF32: A fp32 -> manual convert staging (swizzled stores); Bs always async.
// EPI 0: scatter qkv -> C0/C1/C2 as [B,H,S,DH];  EPI 1: bf16 C0;
// EPI 2: fp32 Cf = val + resid.
// ---------------------------------------------------------------------------
template <int EPI, bool AF32>
__global__ __launch_bounds__(256) void gemm_bt(
    const void* __restrict__ Avp, const bf16* __restrict__ BT,
    const float* __restrict__ bias, int M, int N, int K, int lda,
    bf16* __restrict__ C0, bf16* __restrict__ C1, bf16* __restrict__ C2,
    float* __restrict__ Cf, const bf16* __restrict__ resid)
{
    __shared__ bf16 As[128 * 64];
    __shared__ bf16 Bs[128 * 64];
    const int tid = threadIdx.x;
    const int lane = tid & 63, wave = tid >> 6;
    const int quad = lane >> 4, l16 = lane & 15;
    const int wm = wave >> 1, wn = wave & 1;
    const int nb = N >> 7;
    const int bm = blockIdx.x / nb, bn = blockIdx.x % nb;
    const int m0 = bm << 7, n0 = bn << 7;
    const float* Af = (const float*)Avp;
    const bf16*  Ab = (const bf16*)Avp;
    char* aB = (char*)&As[0];
    char* bB = (char*)&Bs[0];
    const int rsw = l16 & 7;

    f32x4 acc[4][4] = {};

    for (int kt = 0; kt < K; kt += 64) {
        for (int i = 0; i < 4; ++i) {
            int l = (i << 8) + tid;                 // LDS chunk this lane fills
            int r = l >> 3;
            int cbs = ((l & 7) ^ (r & 7)) << 3;     // swizzled source column
            int cu = (i << 8) + (wave << 6);        // wave-uniform chunk base
            if (!AF32)
                async16(&Ab[(size_t)(m0 + r) * lda + kt + cbs], aB + (size_t)cu * 16);
            async16(&BT[(size_t)(n0 + r) * K + kt + cbs], bB + (size_t)cu * 16);
        }
        if (AF32) {
            for (int i = 0; i < 4; ++i) {
                int l = (i << 8) + tid;
                int r = l >> 3;
                int cbs = ((l & 7) ^ (r & 7)) << 3;
                const float* s = &Af[(size_t)(m0 + r) * lda + kt + cbs];
                float4 f0 = *(const float4*)s;
                float4 f1 = *(const float4*)(s + 4);
                bf16x8 tv;
                tv[0] = (bf16)f0.x; tv[1] = (bf16)f0.y;
                tv[2] = (bf16)f0.z; tv[3] = (bf16)f0.w;
                tv[4] = (bf16)f1.x; tv[5] = (bf16)f1.y;
                tv[6] = (bf16)f1.z; tv[7] = (bf16)f1.w;
                *(bf16x8*)&As[l << 3] = tv;         // chunk l (swizzled image)
            }
        }
        __syncthreads();
        for (int kd = 0; kd < 2; ++kd) {
            bf16x8 af[4], bfr[4];
            for (int mi = 0; mi < 4; ++mi) {
                int row = (wm << 6) + (mi << 4) + l16;
                af[mi] = *(const bf16x8*)&As[(row << 6) + ((((kd << 2) + quad) ^ rsw) << 3)];
            }
            for (int ni = 0; ni < 4; ++ni) {
                int row = (wn << 6) + (ni << 4) + l16;
                bfr[ni] = *(const bf16x8*)&Bs[(row << 6) + ((((kd << 2) + quad) ^ rsw) << 3)];
            }
            for (int mi = 0; mi < 4; ++mi)
                for (int ni = 0; ni < 4; ++ni)
                    acc[mi][ni] = MFMA(af[mi], bfr[ni], acc[mi][ni]);
        }
        __syncthreads();
    }

    for (int mi = 0; mi < 4; ++mi) {
        for (int ni = 0; ni < 4; ++ni) {
            for (int r = 0; r < 4; ++r) {
                int row = m0 + (wm << 6) + (mi << 4) + (quad << 2) + r;
                int col = n0 + (wn << 6) + (ni << 4) + l16;
                float v = acc[mi][ni][r] + bias[col];
                if (EPI == 0) {
                    int b = row >> 11, s = row & 2047;
                    int h = col / 192, w = col % 192;
                    int tq = w >> 6, d = w & 63;
                    bf16* dst = (tq == 0) ? C0 : (tq == 1) ? C1 : C2;
                    dst[((((size_t)b * 16 + h) * 2048 + s) << 6) + d] = (bf16)v;
                } else if (EPI == 1) {
                    C0[(size_t)row * N + col] = (bf16)v;
                } else {
                    float rv = (float)resid[(size_t)row * N + col];
                    Cf[(size_t)row * N + col] = v + rv;
                }
            }
        }
    }
}

// ---------------------------------------------------------------------------
// Fused l2norm + head-scale + xpos RoPE, in place, HW transcendentals.
// One wave per (bh, s) row, lane = d.
// ---------------------------------------------------------------------------
__global__ __launch_bounds__(256) void norm_rope(
    bf16* __restrict__ qb, bf16* __restrict__ kb,
    const float* __restrict__ qs, const float* __restrict__ ks)
{
    const int wave = threadIdx.x >> 6, lane = threadIdx.x & 63;
    const int rid = blockIdx.x * 4 + wave;          // 0 .. 262143
    const bool is_k = rid >= 131072;
    const int idx = is_k ? rid - 131072 : rid;      // bh*2048 + s
    const int s = idx & 2047;
    bf16* ptr = (is_k ? kb : qb) + ((size_t)idx << 6);
    const int d = lane;

    float v = (float)ptr[d];
    float ss = v * v;
    for (int o = 1; o < 64; o <<= 1) ss += __shfl_xor(ss, o);
    float t = v * rsqrtf(fmaxf(ss, 1e-24f));
    t *= (is_k ? ks : qs)[d];

    float partner = __shfl_xor(t, 32);
    float rh = (d < 32) ? -partner : partner;       // rotate_half

    const float fi = (float)(d & 31);
    float inv_freq = __builtin_amdgcn_exp2f(fi * -0.4152410118609203f);
    float pos = (float)s * inv_freq;
    float rev = pos * 0.15915494309189535f;         // v_sin takes revolutions
    rev = rev - floorf(rev);
    float sn = __builtin_amdgcn_sinf(rev);
    float cs = __builtin_amdgcn_cosf(rev);
    float base = (2.0f * fi + 25.6f) * (1.0f / 89.6f);
    float power = ((float)s - 1024.0f) * (1.0f / 512.0f);
    if (is_k) power = -power;
    float xsc = __builtin_amdgcn_exp2f(power * __builtin_amdgcn_logf(base));
    ptr[d] = (bf16)((t * cs + rh * sn) * xsc);
}

// ---------------------------------------------------------------------------
// Flash attention, no-max softmax (|score|/8 <= ~19 -> exp <= 1.4e8, fp32-safe;
// 0.125*log2e folded into Q; P = exp2). Row-sums via ones-column MFMA.
// Block = (bh, 128 q-rows); wave owns 32 rows (2 subtiles) -> Ks/Vt frags
// amortized over 2x MFMA. Ks/Vt xor-swizzled async tiles; Ps stride-72 plain.
// ---------------------------------------------------------------------------
__global__ __launch_bounds__(256) void attn(
    const bf16* __restrict__ Q, const bf16* __restrict__ Kb,
    const bf16* __restrict__ VT, bf16* __restrict__ O)
{
    __shared__ bf16 Ks[64 * 64];
    __shared__ bf16 Vt[64 * 64];          // Vt[d][j] image (swizzled chunks)
    __shared__ bf16 Ps[4][2][16][72];     // per-wave, per-subtile P
    const int tid = threadIdx.x;
    const int lane = tid & 63, wave = tid >> 6;
    const int quad = lane >> 4, l16 = lane & 15;
    const int rsw = l16 & 7;
    const int bh = blockIdx.x >> 4;
    const int q0 = (blockIdx.x & 15) << 7;
    const int s_base = q0 + (wave << 5);
    const bf16* Qp = Q + ((size_t)bh << 17);
    const bf16* Kp = Kb + ((size_t)bh << 17);
    const bf16* Vp = VT + ((size_t)bh << 17);

    bf16x8 qf[2][2];
    for (int sub = 0; sub < 2; ++sub) {
        const bf16* qrow = Qp + (size_t)(s_base + (sub << 4) + l16) * 64;
        qf[sub][0] = *(const bf16x8*)&qrow[(quad << 3)];
        qf[sub][1] = *(const bf16x8*)&qrow[32 + (quad << 3)];
        for (int j = 0; j < 8; ++j) {     // fold 0.125 * log2(e)
            qf[sub][0][j] = (bf16)((float)qf[sub][0][j] * 0.1803368801f);
            qf[sub][1][j] = (bf16)((float)qf[sub][1][j] * 0.1803368801f);
        }
    }
    bf16x8 ones = {};
    if (l16 == 0) for (int j = 0; j < 8; ++j) ones[j] = (bf16)1.0f;

    f32x4 oacc[2][4] = {};
    f32x4 lacc[2] = {};
    char* kB = (char*)&Ks[0];
    char* vB = (char*)&Vt[0];

    for (int kt = 0; kt < 2048; kt += 64) {
        __syncthreads();                  // all waves done reading prev tiles
        for (int i = 0; i < 2; ++i) {
            int l = (i << 8) + tid;
            int r = l >> 3;
            int cbs = ((l & 7) ^ (r & 7)) << 3;
            int cu = (i << 8) + (wave << 6);
            async16(&Kp[(size_t)(kt + r) * 64 + cbs], kB + (size_t)cu * 16);
            async16(&Vp[(size_t)r * 2048 + kt + cbs], vB + (size_t)cu * 16);
        }
        __syncthreads();                  // drains vmcnt: tiles resident

        f32x4 sc[2][4];
        for (int nt = 0; nt < 4; ++nt) {
            int row = (nt << 4) + l16;
            bf16x8 kf0 = *(const bf16x8*)&Ks[(row << 6) + ((quad ^ rsw) << 3)];
            bf16x8 kf1 = *(const bf16x8*)&Ks[(row << 6) + (((quad + 4) ^ rsw) << 3)];
            for (int sub = 0; sub < 2; ++sub) {
                f32x4 z = {};
                z = MFMA(qf[sub][0], kf0, z);
                z = MFMA(qf[sub][1], kf1, z);
                sc[sub][nt] = z;
            }
        }
        const int prow = quad << 2;
        for (int sub = 0; sub < 2; ++sub)
            for (int r = 0; r < 4; ++r)
                for (int nt = 0; nt < 4; ++nt)
                    Ps[wave][sub][prow + r][(nt << 4) + l16] =
                        (bf16)__builtin_amdgcn_exp2f(sc[sub][nt][r]);
        // wave-local round-trip: same-wave DS ops are in-order; pin ordering.
        __builtin_amdgcn_wave_barrier();
        bf16x8 pf0[2], pf1[2];
        for (int sub = 0; sub < 2; ++sub) {
            pf0[sub] = *(const bf16x8*)&Ps[wave][sub][l16][(quad << 3)];
            pf1[sub] = *(const bf16x8*)&Ps[wave][sub][l16][32 + (quad << 3)];
        }
        for (int ntd = 0; ntd < 4; ++ntd) {
            int row = (ntd << 4) + l16;
            bf16x8 vf0 = *(const bf16x8*)&Vt[(row << 6) + ((quad ^ rsw) << 3)];
            bf16x8 vf1 = *(const bf16x8*)&Vt[(row << 6) + (((quad + 4) ^ rsw) << 3)];
            for (int sub = 0; sub < 2; ++sub) {
                oacc[sub][ntd] = MFMA(pf0[sub], vf0, oacc[sub][ntd]);
                oacc[sub][ntd] = MFMA(pf1[sub], vf1, oacc[sub][ntd]);
            }
        }
        for (int sub = 0; sub < 2; ++sub) {
            lacc[sub] = MFMA(pf0[sub], ones, lacc[sub]);
            lacc[sub] = MFMA(pf1[sub], ones, lacc[sub]);
        }
    }

    const int b = bh >> 4, h = bh & 15;
    for (int sub = 0; sub < 2; ++sub)
        for (int r = 0; r < 4; ++r) {
            float l = __shfl(lacc[sub][r], quad << 4);   // col-0 lane of quad
            float inv_l = 1.0f / l;
            int srow = s_base + (sub << 4) + (quad << 2) + r;
            for (int ntd = 0; ntd < 4; ++ntd) {
                int d = (ntd << 4) + l16;
                O[((((size_t)b * 2048 + srow) * 16) + h) * 64 + d] =
                    (bf16)(oacc[sub][ntd][r] * inv_l);
            }
        }
}

// ---------------------------------------------------------------------------
// LayerNorm over rows of [8192, 1024]; gamma/beta fp32.
// ---------------------------------------------------------------------------
__global__ __launch_bounds__(256) void layernorm(
    const bf16* __restrict__ x, const float* __restrict__ g,
    const float* __restrict__ b, bf16* __restrict__ y)
{
    __shared__ float red[8];
    const int row = blockIdx.x;
    const int t = threadIdx.x;
    const bf16* xr = x + ((size_t)row << 10);
    bf16x4 xv = *(const bf16x4*)&xr[t << 2];
    float v[4], s = 0.0f, sq = 0.0f;
    for (int i = 0; i < 4; ++i) { v[i] = (float)xv[i]; s += v[i]; sq += v[i] * v[i]; }
    for (int o = 1; o < 64; o <<= 1) { s += __shfl_xor(s, o); sq += __shfl_xor(sq, o); }
    const int wave = t >> 6, lane = t & 63;
    if (lane == 0) { red[wave] = s; red[4 + wave] = sq; }
    __syncthreads();
    s  = red[0] + red[1] + red[2] + red[3];
    sq = red[4] + red[5] + red[6] + red[7];
    float mu = s * (1.0f / 1024.0f);
    float var = fmaxf(sq * (1.0f / 1024.0f) - mu * mu, 0.0f);
    float rstd = rsqrtf(var + 1e-5f);
    bf16x4 ov;
    for (int i = 0; i < 4; ++i) {
        int c = (t << 2) + i;
        ov[i] = (bf16)((v[i] - mu) * rstd * g[c] + b[c]);
    }
    *(bf16x4*)(y + ((size_t)row << 10) + (t << 2)) = ov;
}

// ---------------------------------------------------------------------------
// SwiGLU in place: h[r][c] = silu(h[r][c+2048]) * h[r][c], h is [8192,4096].
// ---------------------------------------------------------------------------
__global__ __launch_bounds__(256) void swiglu(bf16* __restrict__ h)
{
    size_t i = ((size_t)blockIdx.x * 256 + threadIdx.x) * 8;
    size_t row = i >> 11, c = i & 2047;
    bf16* hr = h + (row << 12);
    bf16x8 xv = *(const bf16x8*)&hr[c];
    bf16x8 gv = *(const bf16x8*)&hr[c + 2048];
    bf16x8 ov;
    for (int j = 0; j < 8; ++j) {
        float xf = (float)xv[j], gf = (float)gv[j];
        ov[j] = (bf16)(gf / (1.0f + __expf(-gf)) * xf);
    }
    *(bf16x8*)&hr[c] = ov;
}

// ---------------------------------------------------------------------------
// Orchestration. ws layout (bytes), peak 92 MiB:
//   W2T 0..4M | ln 4..20M | W1T 20..28M | q 28..44M k 44..60M v 60..76M
//   WqkvT 76..82M (dead after QKV gemm) | vt 76..92M (after transpose_v)
//   attn 60..76M (overlay v, dead after transpose_v)
//   h 28..92M (overlay q/k/vt/attn after LN consumed attn)
// ---------------------------------------------------------------------------
extern "C" void kernel_launch(void* const* d_in, const int* in_sizes, int n_in,
                              void* d_out, int out_size, void* d_ws, size_t ws_size,
                              hipStream_t stream) {
    (void)in_sizes; (void)n_in; (void)out_size;
    const float* q    = (const float*)d_in[0];
    const float* Wqkv = (const float*)d_in[3];
    const float* bqkv = (const float*)d_in[4];
    const float* qsc  = (const float*)d_in[5];
    const float* ksc  = (const float*)d_in[6];
    const float* lng  = (const float*)d_in[7];
    const float* lnb  = (const float*)d_in[8];
    const float* W1   = (const float*)d_in[9];
    const float* b1   = (const float*)d_in[10];
    const float* W2   = (const float*)d_in[11];
    const float* b2   = (const float*)d_in[12];
    float* out = (float*)d_out;

    const size_t MB = 1024 * 1024;
    if (ws_size < 92 * MB) {
        fill_sentinel<<<8192, 256, 0, stream>>>(out);
        return;
    }

    char* ws = (char*)d_ws;
    bf16* W2T      = (bf16*)(ws + 0);
    bf16* ln_buf   = (bf16*)(ws + 4  * MB);
    bf16* W1T      = (bf16*)(ws + 20 * MB);
    bf16* q_buf    = (bf16*)(ws + 28 * MB);
    bf16* k_buf    = (bf16*)(ws + 44 * MB);
    bf16* v_buf    = (bf16*)(ws + 60 * MB);
    bf16* WqkvT    = (bf16*)(ws + 76 * MB);
    bf16* vt_buf   = (bf16*)(ws + 76 * MB);  // overlays WqkvT (dead post-QKV)
    bf16* attn_buf = (bf16*)(ws + 60 * MB);  // overlays v_buf (dead post-transpose_v)
    bf16* h_buf    = (bf16*)(ws + 28 * MB);  // overlays q/k/vt/attn

    transpose_f32_bf16<<<512,  256, 0, stream>>>(W2,   W2T,   2048, 1024);
    transpose_f32_bf16<<<1024, 256, 0, stream>>>(W1,   W1T,   1024, 4096);
    transpose_f32_bf16<<<768,  256, 0, stream>>>(Wqkv, WqkvT, 1024, 3072);

    gemm_bt<0, true><<<1536, 256, 0, stream>>>(q, WqkvT, bqkv, 8192, 3072, 1024, 1024,
                                               q_buf, k_buf, v_buf, nullptr, nullptr);
    norm_rope<<<65536, 256, 0, stream>>>(q_buf, k_buf, qsc, ksc);
    transpose_v<<<2048, 256, 0, stream>>>(v_buf, vt_buf);
    attn<<<1024, 256, 0, stream>>>(q_buf, k_buf, vt_buf, attn_buf);
    layernorm<<<8192, 256, 0, stream>>>(attn_buf, lng, lnb, ln_buf);
    gemm_bt<1, false><<<2048, 256, 0, stream>>>(ln_buf, W1T, b1, 8192, 4096, 1024, 1024,
                                                h_buf, nullptr, nullptr, nullptr, nullptr);
    swiglu<<<8192, 256, 0, stream>>>(h_buf);
    gemm_bt<2, false><<<512, 256, 0, stream>>>(h_buf, W2T, b2, 8192, 1024, 2048, 4096,
                                               nullptr, nullptr, nullptr, out, ln_buf);
}